// Round 2
// baseline (266.667 us; speedup 1.0000x reference)
//
#include <hip/hip_runtime.h>

// DISCO S2 conv, round 8: dual-pipe gather + software-pipelined meta.
// prep: x -> xT f16 [b][lat][lon][8 chunks x 8c], chunk pos = ch ^ (lon&7).
//   meta split into yz int2 {yOrW, lonb} and pk16 u16: taps 0..11 carry the
//   ABSOLUTE xT byte offset (global-load path), taps 12..23 the LDS-relative
//   slot offset. Both share the same wrap arithmetic (ROWB = row bytes).
// main: per k: compute all 24 addresses (frees meta SGPRs) -> s_load k+1 meta
//   (latency hidden under load/fma phase, no mid-phase lgkm drain) -> issue
//   12 taps x 2 global_load_dwordx4 from xT (L1/L2, vmcnt-pipelined) and
//   12 taps x 2 ds_read_b128 from LDS -> fma global half (taps 0..11, original
//   order), fma LDS half (12..23) -> prefetch k+1 pk -> 8x mfma 16x16x32_f16.
//   LDS gather instr count halves vs round 7; two load pipes overlap.

#define NB    2
#define CIN   64
#define COUT  64
#define KS    9
#define NLAT  181
#define NLON  360
#define NPER  24
#define NGLB  12                                          // taps 0..11  -> global
#define NLDS  12                                          // taps 12..23 -> LDS

typedef _Float16 f16;
typedef _Float16 f16x8 __attribute__((ext_vector_type(8)));
typedef float    f32x4 __attribute__((ext_vector_type(4)));
typedef float    f32x2 __attribute__((ext_vector_type(2)));
typedef unsigned int u32;
typedef unsigned short u16;
typedef u32 u32x4 __attribute__((ext_vector_type(4)));

#define ROWB      46080                                   // 360*64*2 B per lat row
#define XT_BYTES  ((size_t)NB * NLAT * NLON * 64 * 2)     // 16,680,960
#define WT_BYTES  (KS * 64 * 64 * 2)                      // 73,728
#define NMETA     (KS * NLAT * NPER)                      // 39,096
#define YZ_BYTES  (NMETA * 8)                             // 312,768
#define XS_BYTES  (3 * ROWB)                              // 138,240 B LDS

#define U0  (NB * NLAT * 180 * 8)                         // 521,280 threads
#define G0  ((U0 + 255) / 256)                            // 2037
#define G1  ((KS * 4096 + 255) / 256)                     // 144
#define G2  ((NMETA + 255) / 256)                         // 153

// ---------------- prep ------------------------------------------------------
__global__ __launch_bounds__(256) void prep_kernel(
    const float* __restrict__ x, const float* __restrict__ weight,
    const float* __restrict__ psi_vals, const int* __restrict__ psi_lat_in,
    const int* __restrict__ psi_lon_in,
    f16* __restrict__ xT, f16* __restrict__ wT,
    int2* __restrict__ yz, u16* __restrict__ pk16)
{
    const int bid = blockIdx.x, tid = threadIdx.x;
    if (bid < G0) {                           // x transpose: 2 lon x 8 c per thread
        const int u = bid * 256 + tid;
        if (u >= U0) return;
        const int ch   = u & 7;
        const int v    = u >> 3;
        const int lon2 = v % 180;
        const int w    = v / 180;
        const int lat  = w % NLAT;
        const int b    = w / NLAT;
        const int lon0 = lon2 * 2;
        const float* src = x + ((size_t)(b * CIN + ch * 8) * NLAT + lat) * NLON + lon0;
        f16x8 v0, v1;
#pragma unroll
        for (int j = 0; j < 8; ++j) {
            const f32x2 lv = *(const f32x2*)&src[(size_t)j * NLAT * NLON];
            v0[j] = (f16)lv[0];
            v1[j] = (f16)lv[1];
        }
        const int pos0 = ch ^ (lon0 & 7);     // baked chunk swizzle
        f16* xd = xT + ((size_t)(b * NLAT + lat) * NLON + lon0) * 64;
        *(f16x8*)&xd[pos0 * 8]            = v0;
        *(f16x8*)&xd[64 + (pos0 ^ 1) * 8] = v1;
        return;
    }
    if (bid < G0 + G1) {                      // wT[k][f][c] = W[f][c][k]
        const int e = (bid - G0) * 256 + tid;
        if (e < KS * 4096) {
            int c = e & 63, f = (e >> 6) & 63, k = e >> 12;
            wT[e] = (f16)weight[((size_t)(f * 64 + c)) * KS + k];
        }
        return;
    }
    {                                         // split tap metadata, [k][lat][t]
        const int e = (bid - G0 - G1) * 256 + tid;
        if (e < NMETA) {
            int lat = (e / NPER) % NLAT;
            int t   = e % NPER;
            f16 pvh = (f16)psi_vals[e];
            pk16[e] = __builtin_bit_cast(u16, pvh);
            int lonb = psi_lon_in[e] << 7;    // lon*128 B
            int2 m;
            m.y = lonb;                       // wrap compare value
            m.x = (t < NGLB)
                ? (psi_lat_in[e] * ROWB + lonb)                 // absolute (global)
                : ((psi_lat_in[e] - lat + 1) * ROWB + lonb);    // slot-rel (LDS)
            yz[e] = m;
        }
    }
}

// ---------------- main ------------------------------------------------------
__global__ __launch_bounds__(768, 3) void disco_main(
    const f16* __restrict__ xT, const f16* __restrict__ wT,
    const int2* __restrict__ yz, const u16* __restrict__ pk16,
    const float* __restrict__ bias, float* __restrict__ out)
{
    extern __shared__ char xs[];              // [slot 3][lon 360][8 chunks x 8c]
    const int tid  = threadIdx.x;
    const int lane = tid & 63, wave = tid >> 6;   // 12 waves
    const int pn   = lane & 15, q = lane >> 4;
    const int half2 = blockIdx.x, lat = blockIdx.y, b = blockIdx.z;

    const int tile = half2 * 12 + wave;       // 0..11 | 12..23 (23 = dummy)
    const bool act = tile < 23;               // wave-uniform
    const int p  = tile * 16 + pn;            // <= 367; >=360 masked at store
    const int pl = p >= NLON ? p - NLON : p;
    const u32 plq  = (u32)((pl << 7) + (q << 4)); // p*128 + q*16
    const u32 plqm = plq - (u32)ROWB;             // wrapped variant
    const u32 thr  = (u32)((NLON - pl) << 7);     // wrap iff lon*128 >= thr

    const int rr0 = lat > 0 ? lat - 1 : 0;
    const int rr2 = lat < NLAT - 1 ? lat + 1 : NLAT - 1;
    const char* xgb = (const char*)xT + (size_t)b * ((size_t)NLAT * ROWB);

    // single stage: 3 rows x 64 channels (2880 f16x8 units per row)
    {
        const size_t bb = (size_t)b * NLAT;
        const f16* s0 = xT + (bb + rr0) * NLON * 64;
        const f16* s1 = xT + (bb + lat) * NLON * 64;
        const f16* s2 = xT + (bb + rr2) * NLON * 64;
        for (int i = tid; i < 2880; i += 768) {
            *(f16x8*)&xs[i * 16]             = *(const f16x8*)&s0[i * 8];
            *(f16x8*)&xs[ROWB + i * 16]      = *(const f16x8*)&s1[i * 8];
            *(f16x8*)&xs[2 * ROWB + i * 16]  = *(const f16x8*)&s2[i * 8];
        }
    }

    // preload k=0 meta (s_load latency overlaps the stage + barrier)
    int2 yzb[NPER];
    u32  pkw[NPER / 2];
    {
        const int2* yzp = yz + (size_t)lat * NPER;
        const u32*  pkp = (const u32*)(pk16 + (size_t)lat * NPER);
#pragma unroll
        for (int j = 0; j < NPER; ++j) yzb[j] = yzp[j];
#pragma unroll
        for (int j = 0; j < NPER / 2; ++j) pkw[j] = pkp[j];
    }

    __syncthreads();                          // the ONLY barrier

    f32x4 D[4];
#pragma unroll
    for (int ft = 0; ft < 4; ++ft) D[ft] = (f32x4){0.f, 0.f, 0.f, 0.f};

    if (act) {
#pragma unroll 1
        for (int k = 0; k < KS; ++k) {
            const int kn = (k < KS - 1) ? (k + 1) : 0;   // k=8 prefetch is a harmless re-read

            // -- addresses for all 24 taps (frees yzb) --
            u32 aG[NGLB], aL[NLDS];
#pragma unroll
            for (int j = 0; j < NGLB; ++j) {
                u32 ad = ((u32)yzb[j].y >= thr) ? plqm : plq;
                u32 t  = (u32)yzb[j].x + ad;
                aG[j]  = t ^ ((t >> 3) & 0x70u);
            }
#pragma unroll
            for (int j = 0; j < NLDS; ++j) {
                u32 ad = ((u32)yzb[NGLB + j].y >= thr) ? plqm : plq;
                u32 t  = (u32)yzb[NGLB + j].x + ad;
                aL[j]  = t ^ ((t >> 3) & 0x70u);
            }
            // -- prefetch next-k yz: latency hides under loads+fma below --
            {
                const int2* yzp = yz + ((size_t)kn * NLAT + lat) * NPER;
#pragma unroll
                for (int j = 0; j < NPER; ++j) yzb[j] = yzp[j];
            }

            // -- issue global-path gather (vmcnt pipe, taps 0..11) --
            f16x8 xg0[NGLB], xg1[NGLB];
#pragma unroll
            for (int j = 0; j < NGLB; ++j) {
                xg0[j] = *(const f16x8*)(xgb + aG[j]);
                xg1[j] = *(const f16x8*)(xgb + (aG[j] ^ 64u));
            }
            // -- A frags (vmem, L1-hot) --
            f16x8 Af0[4], Af1[4];
            const f16* wk = wT + (size_t)k * 4096 + q * 8;
#pragma unroll
            for (int ft = 0; ft < 4; ++ft) {
                Af0[ft] = *(const f16x8*)&wk[(ft * 16 + pn) * 64];
                Af1[ft] = *(const f16x8*)&wk[32 + (ft * 16 + pn) * 64];
            }
            // -- issue LDS-path gather (taps 12..23) --
            f16x8 xv0[NLDS], xv1[NLDS];
#pragma unroll
            for (int j = 0; j < NLDS; ++j) {
                xv0[j] = *(const f16x8*)(xs + aL[j]);
                xv1[j] = *(const f16x8*)(xs + (aL[j] ^ 64u));
            }

            // -- fma: global taps 0..11 first (original summation order) --
            f16x8 acc0 = (f16x8){0, 0, 0, 0, 0, 0, 0, 0};
            f16x8 acc1 = (f16x8){0, 0, 0, 0, 0, 0, 0, 0};
#pragma unroll
            for (int j = 0; j < NGLB; ++j) {
                u32 w  = pkw[j >> 1];
                u32 pk = (j & 1) ? ((w & 0xffff0000u) | (w >> 16))
                                 : ((w << 16) | (w & 0xffffu));
                u32x4 pkv = {pk, pk, pk, pk};
                f16x8 pf = __builtin_bit_cast(f16x8, pkv);
                acc0 += xg0[j] * pf;                      // v_pk_fma_f16
                acc1 += xg1[j] * pf;
            }
#pragma unroll
            for (int j = 0; j < NLDS; ++j) {
                const int t = NGLB + j;
                u32 w  = pkw[t >> 1];
                u32 pk = (t & 1) ? ((w & 0xffff0000u) | (w >> 16))
                                 : ((w << 16) | (w & 0xffffu));
                u32x4 pkv = {pk, pk, pk, pk};
                f16x8 pf = __builtin_bit_cast(f16x8, pkv);
                acc0 += xv0[j] * pf;
                acc1 += xv1[j] * pf;
            }
            // -- prefetch next-k pk (pkw dead after fma) --
            {
                const u32* pkp = (const u32*)(pk16 + ((size_t)kn * NLAT + lat) * NPER);
#pragma unroll
                for (int j = 0; j < NPER / 2; ++j) pkw[j] = pkp[j];
            }
            // -- mfma --
#pragma unroll
            for (int ft = 0; ft < 4; ++ft) {
                D[ft] = __builtin_amdgcn_mfma_f32_16x16x32_f16(Af0[ft], acc0, D[ft], 0, 0, 0);
                D[ft] = __builtin_amdgcn_mfma_f32_16x16x32_f16(Af1[ft], acc1, D[ft], 0, 0, 0);
            }
        }
    }

    // epilogue: D[m=f][n=p], lane: col = pn, rows (lane>>4)*4 + r
    if (act && p < NLON) {
#pragma unroll
        for (int ft = 0; ft < 4; ++ft)
#pragma unroll
            for (int r = 0; r < 4; ++r) {
                const int f = ft * 16 + q * 4 + r;
                out[((size_t)(b * COUT + f) * NLAT + lat) * NLON + p] = D[ft][r] + bias[f];
            }
    }
}

extern "C" void kernel_launch(void* const* d_in, const int* in_sizes, int n_in,
                              void* d_out, int out_size, void* d_ws, size_t ws_size,
                              hipStream_t stream) {
    const float* x          = (const float*)d_in[0];
    const float* psi_vals   = (const float*)d_in[1];
    const float* weight     = (const float*)d_in[2];
    const float* bias       = (const float*)d_in[3];
    const int*   psi_lat_in = (const int*)d_in[6];
    const int*   psi_lon_in = (const int*)d_in[7];
    float* out = (float*)d_out;

    f16*  xT   = (f16*)d_ws;
    f16*  wT   = (f16*)((char*)d_ws + XT_BYTES);
    int2* yzm  = (int2*)((char*)d_ws + XT_BYTES + WT_BYTES);
    u16*  pk16 = (u16*)((char*)d_ws + XT_BYTES + WT_BYTES + YZ_BYTES);

    (void)hipFuncSetAttribute((const void*)disco_main,
                              hipFuncAttributeMaxDynamicSharedMemorySize, XS_BYTES);

    prep_kernel<<<dim3(G0 + G1 + G2), 256, 0, stream>>>(
        x, weight, psi_vals, psi_lat_in, psi_lon_in, xT, wT, yzm, pk16);
    disco_main<<<dim3(2, NLAT, NB), 768, XS_BYTES, stream>>>(
        xT, wT, yzm, pk16, bias, out);
}

// Round 4
// 201.070 us; speedup vs baseline: 1.3262x; 1.3262x over previous
//
#include <hip/hip_runtime.h>

// DISCO S2 conv, round 10 = round 9 with staging reverted to the proven
// vector-load form (round-9's global_load_lds stage is the prime suspect in
// the container failure; it was the only never-passed element).
// Under test (isolated): software-pipelined meta. Per k:
//   [addr x24 from SGPRs -> frees meta] -> [s_load k+1 yz (latency hidden)] ->
//   [A-frags] -> [3 groups x 8 taps: 16 ds_read_b128 in flight, fma via
//   v_pk_fma_f16 with SGPR pk operand, NO SMEM between reads -> no lgkm drain]
//   -> [s_load k+1 pk] -> [8x mfma 16x16x32_f16].
// Everything else identical to round 7 (108 us): all-LDS gather, 138 KB LDS,
// one barrier, merged c-halves.

#define NB    2
#define CIN   64
#define COUT  64
#define KS    9
#define NLAT  181
#define NLON  360
#define NPER  24

typedef _Float16 f16;
typedef _Float16 f16x8 __attribute__((ext_vector_type(8)));
typedef float    f32x4 __attribute__((ext_vector_type(4)));
typedef float    f32x2 __attribute__((ext_vector_type(2)));
typedef unsigned int u32;
typedef unsigned short u16;
typedef u32 u32x4 __attribute__((ext_vector_type(4)));

#define ROWB      46080                                   // 360*64*2 B per lat row
#define XT_BYTES  ((size_t)NB * NLAT * NLON * 64 * 2)     // 16,680,960
#define WT_BYTES  (KS * 64 * 64 * 2)                      // 73,728
#define NMETA     (KS * NLAT * NPER)                      // 39,096
#define YZ_BYTES  (NMETA * 8)                             // 312,768
#define XS_BYTES  (3 * ROWB)                              // 138,240 B LDS

#define U0  (NB * NLAT * 180 * 8)                         // 521,280 threads
#define G0  ((U0 + 255) / 256)                            // 2037
#define G1  ((KS * 4096 + 255) / 256)                     // 144
#define G2  ((NMETA + 255) / 256)                         // 153

// ---------------- prep ------------------------------------------------------
__global__ __launch_bounds__(256) void prep_kernel(
    const float* __restrict__ x, const float* __restrict__ weight,
    const float* __restrict__ psi_vals, const int* __restrict__ psi_lat_in,
    const int* __restrict__ psi_lon_in,
    f16* __restrict__ xT, f16* __restrict__ wT,
    int2* __restrict__ yz, u16* __restrict__ pk16)
{
    const int bid = blockIdx.x, tid = threadIdx.x;
    if (bid < G0) {                           // x transpose: 2 lon x 8 c per thread
        const int u = bid * 256 + tid;
        if (u >= U0) return;
        const int ch   = u & 7;
        const int v    = u >> 3;
        const int lon2 = v % 180;
        const int w    = v / 180;
        const int lat  = w % NLAT;
        const int b    = w / NLAT;
        const int lon0 = lon2 * 2;
        const float* src = x + ((size_t)(b * CIN + ch * 8) * NLAT + lat) * NLON + lon0;
        f16x8 v0, v1;
#pragma unroll
        for (int j = 0; j < 8; ++j) {
            const f32x2 lv = *(const f32x2*)&src[(size_t)j * NLAT * NLON];
            v0[j] = (f16)lv[0];
            v1[j] = (f16)lv[1];
        }
        const int pos0 = ch ^ (lon0 & 7);     // baked chunk swizzle
        f16* xd = xT + ((size_t)(b * NLAT + lat) * NLON + lon0) * 64;
        *(f16x8*)&xd[pos0 * 8]            = v0;
        *(f16x8*)&xd[64 + (pos0 ^ 1) * 8] = v1;
        return;
    }
    if (bid < G0 + G1) {                      // wT[k][f][c] = W[f][c][k]
        const int e = (bid - G0) * 256 + tid;
        if (e < KS * 4096) {
            int c = e & 63, f = (e >> 6) & 63, k = e >> 12;
            wT[e] = (f16)weight[((size_t)(f * 64 + c)) * KS + k];
        }
        return;
    }
    {                                         // split tap metadata, [k][lat][t]
        const int e = (bid - G0 - G1) * 256 + tid;
        if (e < NMETA) {
            int lat = (e / NPER) % NLAT;
            f16 pvh = (f16)psi_vals[e];
            pk16[e] = __builtin_bit_cast(u16, pvh);
            int lonb = psi_lon_in[e] << 7;    // lon*128 B
            int2 m;
            m.y = lonb;                       // wrap compare value
            m.x = (psi_lat_in[e] - lat + 1) * ROWB + lonb;  // slot-relative
            yz[e] = m;
        }
    }
}

// ---------------- main ------------------------------------------------------
__global__ __launch_bounds__(768, 3) void disco_main(
    const f16* __restrict__ xT, const f16* __restrict__ wT,
    const int2* __restrict__ yz, const u16* __restrict__ pk16,
    const float* __restrict__ bias, float* __restrict__ out)
{
    extern __shared__ char xs[];              // [slot 3][lon 360][8 chunks x 8c]
    const int tid  = threadIdx.x;
    const int lane = tid & 63, wave = tid >> 6;   // 12 waves
    const int pn   = lane & 15, q = lane >> 4;
    const int half2 = blockIdx.x, lat = blockIdx.y, b = blockIdx.z;

    const int tile = half2 * 12 + wave;       // 0..11 | 12..23 (23 = dummy)
    const bool act = tile < 23;               // wave-uniform
    const int p  = tile * 16 + pn;            // <= 367; >=360 masked at store
    const int pl = p >= NLON ? p - NLON : p;
    const u32 plq  = (u32)((pl << 7) + (q << 4)); // p*128 + q*16
    const u32 plqm = plq - (u32)ROWB;             // wrapped variant
    const u32 thr  = (u32)((NLON - pl) << 7);     // wrap iff lon*128 >= thr

    const int rr0 = lat > 0 ? lat - 1 : 0;
    const int rr2 = lat < NLAT - 1 ? lat + 1 : NLAT - 1;

    // single stage: 3 rows x 64 channels (2880 f16x8 units per row), proven form
    {
        const size_t bb = (size_t)b * NLAT;
        const f16* s0 = xT + (bb + rr0) * NLON * 64;
        const f16* s1 = xT + (bb + lat) * NLON * 64;
        const f16* s2 = xT + (bb + rr2) * NLON * 64;
        for (int i = tid; i < 2880; i += 768) {
            *(f16x8*)&xs[i * 16]             = *(const f16x8*)&s0[i * 8];
            *(f16x8*)&xs[ROWB + i * 16]      = *(const f16x8*)&s1[i * 8];
            *(f16x8*)&xs[2 * ROWB + i * 16]  = *(const f16x8*)&s2[i * 8];
        }
    }

    // preload k=0 meta (s_load latency overlaps the stage + barrier)
    int2 yzb[NPER];
    u32  pkw[NPER / 2];
    {
        const int2* yzp = yz + (size_t)lat * NPER;
        const u32*  pkp = (const u32*)(pk16 + (size_t)lat * NPER);
#pragma unroll
        for (int j = 0; j < NPER; ++j) yzb[j] = yzp[j];
#pragma unroll
        for (int j = 0; j < NPER / 2; ++j) pkw[j] = pkp[j];
    }

    __syncthreads();                          // the ONLY barrier

    f32x4 D[4];
#pragma unroll
    for (int ft = 0; ft < 4; ++ft) D[ft] = (f32x4){0.f, 0.f, 0.f, 0.f};

    if (act) {
#pragma unroll 1
        for (int k = 0; k < KS; ++k) {
            const int kn = (k < KS - 1) ? (k + 1) : 0;   // k=8 prefetch: harmless re-read

            // -- addresses for all 24 taps (frees yzb SGPRs) --
            u32 aL[NPER];
#pragma unroll
            for (int j = 0; j < NPER; ++j) {
                u32 ad = ((u32)yzb[j].y >= thr) ? plqm : plq;
                u32 t  = (u32)yzb[j].x + ad;
                aL[j]  = t ^ ((t >> 3) & 0x70u);
            }
            // -- prefetch next-k yz: completes during this k's reads/fma --
            {
                const int2* yzp = yz + ((size_t)kn * NLAT + lat) * NPER;
#pragma unroll
                for (int j = 0; j < NPER; ++j) yzb[j] = yzp[j];
            }

            // -- A frags (vmem pipe, L1-hot) --
            f16x8 Af0[4], Af1[4];
            const f16* wk = wT + (size_t)k * 4096 + q * 8;
#pragma unroll
            for (int ft = 0; ft < 4; ++ft) {
                Af0[ft] = *(const f16x8*)&wk[(ft * 16 + pn) * 64];
                Af1[ft] = *(const f16x8*)&wk[32 + (ft * 16 + pn) * 64];
            }

            // -- gather + fma: 3 groups x 8 taps, no SMEM ops in between --
            f16x8 acc0 = (f16x8){0, 0, 0, 0, 0, 0, 0, 0};   // c = q*8+j
            f16x8 acc1 = (f16x8){0, 0, 0, 0, 0, 0, 0, 0};   // c = 32+q*8+j
#pragma unroll
            for (int g = 0; g < 3; ++g) {
                f16x8 xv0[8], xv1[8];                       // 16 b128 in flight
#pragma unroll
                for (int j = 0; j < 8; ++j) {
                    const u32 a = aL[g * 8 + j];
                    xv0[j] = *(const f16x8*)(xs + a);
                    xv1[j] = *(const f16x8*)(xs + (a ^ 64u));
                }
#pragma unroll
                for (int j = 0; j < 8; ++j) {
                    const int t = g * 8 + j;
                    u32 w  = pkw[t >> 1];
                    u32 pk = (t & 1) ? ((w & 0xffff0000u) | (w >> 16))
                                     : ((w << 16) | (w & 0xffffu));   // s_pack_*
                    u32x4 pkv = {pk, pk, pk, pk};
                    f16x8 pf = __builtin_bit_cast(f16x8, pkv);
                    acc0 += xv0[j] * pf;                    // v_pk_fma_f16, SGPR src
                    acc1 += xv1[j] * pf;
                }
            }
            // -- prefetch next-k pk (pkw dead after fma) --
            {
                const u32* pkp = (const u32*)(pk16 + ((size_t)kn * NLAT + lat) * NPER);
#pragma unroll
                for (int j = 0; j < NPER / 2; ++j) pkw[j] = pkp[j];
            }
            // -- mfma --
#pragma unroll
            for (int ft = 0; ft < 4; ++ft) {
                D[ft] = __builtin_amdgcn_mfma_f32_16x16x32_f16(Af0[ft], acc0, D[ft], 0, 0, 0);
                D[ft] = __builtin_amdgcn_mfma_f32_16x16x32_f16(Af1[ft], acc1, D[ft], 0, 0, 0);
            }
        }
    }

    // epilogue: D[m=f][n=p], lane: col = pn, rows (lane>>4)*4 + r
    if (act && p < NLON) {
#pragma unroll
        for (int ft = 0; ft < 4; ++ft)
#pragma unroll
            for (int r = 0; r < 4; ++r) {
                const int f = ft * 16 + q * 4 + r;
                out[((size_t)(b * COUT + f) * NLAT + lat) * NLON + p] = D[ft][r] + bias[f];
            }
    }
}

extern "C" void kernel_launch(void* const* d_in, const int* in_sizes, int n_in,
                              void* d_out, int out_size, void* d_ws, size_t ws_size,
                              hipStream_t stream) {
    const float* x          = (const float*)d_in[0];
    const float* psi_vals   = (const float*)d_in[1];
    const float* weight     = (const float*)d_in[2];
    const float* bias       = (const float*)d_in[3];
    const int*   psi_lat_in = (const int*)d_in[6];
    const int*   psi_lon_in = (const int*)d_in[7];
    float* out = (float*)d_out;

    f16*  xT   = (f16*)d_ws;
    f16*  wT   = (f16*)((char*)d_ws + XT_BYTES);
    int2* yzm  = (int2*)((char*)d_ws + XT_BYTES + WT_BYTES);
    u16*  pk16 = (u16*)((char*)d_ws + XT_BYTES + WT_BYTES + YZ_BYTES);

    (void)hipFuncSetAttribute((const void*)disco_main,
                              hipFuncAttributeMaxDynamicSharedMemorySize, XS_BYTES);

    prep_kernel<<<dim3(G0 + G1 + G2), 256, 0, stream>>>(
        x, weight, psi_vals, psi_lat_in, psi_lon_in, xT, wT, yzm, pk16);
    disco_main<<<dim3(2, NLAT, NB), 768, XS_BYTES, stream>>>(
        xT, wT, yzm, pk16, bias, out);
}

// Round 7
// 192.461 us; speedup vs baseline: 1.3856x; 1.0447x over previous
//
#include <hip/hip_runtime.h>

// DISCO S2 conv, round 13 = round 11 resubmitted again (two consecutive GPU
// acquisition timeouts; kernel has never run). Main reverted to the proven
// round-7 kernel (108 us, measured twice); ALL changes this round are in prep,
// to isolate and attack the constant ~85 us dur-minus-main gap.
// prep x-transpose rewrite: thread = (b,lat,lon4,ch): 8x f32x4 coalesced loads
//   (16B/lane, was 8B strided), in-register 8x4 transpose, 4x f16x8 stores
//   (8 lanes -> one contiguous 128B line). 4370 -> 1316 blocks, half the
//   memory requests.
// main: 768-thr blocks, 138 KB LDS (3 rows x 64c), one barrier, merged
//   c-halves, int4 meta s_load in 4-tap groups, 8 ds_read_b128 in flight.

#define NB    2
#define CIN   64
#define COUT  64
#define KS    9
#define NLAT  181
#define NLON  360
#define NPER  24

typedef _Float16 f16;
typedef _Float16 f16x8 __attribute__((ext_vector_type(8)));
typedef float    f32x4 __attribute__((ext_vector_type(4)));
typedef unsigned int u32;
typedef unsigned short u16;
typedef u32 u32x4 __attribute__((ext_vector_type(4)));

#define ROWB      46080                                   // 360*64*2 B per lat row
#define XT_BYTES  ((size_t)NB * NLAT * NLON * 64 * 2)     // 16,680,960
#define WT_BYTES  (KS * 64 * 64 * 2)                      // 73,728
#define NMETA     (KS * NLAT * NPER)                      // 39,096
#define XS_BYTES  (3 * ROWB)                              // 138,240 B LDS

#define U0  (NB * NLAT * 90 * 8)                          // 260,640 threads (4 lon each)
#define G0  ((U0 + 255) / 256)                            // 1019
#define G1  ((KS * 4096 + 255) / 256)                     // 144
#define G2  ((NMETA + 255) / 256)                         // 153

// ---------------- prep ------------------------------------------------------
__global__ __launch_bounds__(256) void prep_kernel(
    const float* __restrict__ x, const float* __restrict__ weight,
    const float* __restrict__ psi_vals, const int* __restrict__ psi_lat_in,
    const int* __restrict__ psi_lon_in,
    f16* __restrict__ xT, f16* __restrict__ wT, int4* __restrict__ meta)
{
    const int bid = blockIdx.x, tid = threadIdx.x;
    if (bid < G0) {                           // x transpose: 4 lon x 8 c per thread
        const int u = bid * 256 + tid;
        if (u >= U0) return;
        const int ch   = u & 7;               // channel chunk 0..7
        const int v    = u >> 3;
        const int lon4 = v % 90;
        const int w    = v / 90;
        const int lat  = w % NLAT;
        const int b    = w / NLAT;
        const int lon0 = lon4 * 4;            // 16B-aligned f32 column
        const float* src = x + ((size_t)(b * CIN + ch * 8) * NLAT + lat) * NLON + lon0;
        f32x4 L[8];
#pragma unroll
        for (int j = 0; j < 8; ++j)           // 8 coalesced 16B loads
            L[j] = *(const f32x4*)&src[(size_t)j * NLAT * NLON];
        f16* xd = xT + ((size_t)(b * NLAT + lat) * NLON + lon0) * 64;
        const int pbase = ch ^ (lon0 & 7);    // (lon0+dl)&7 == (lon0&7)^dl (lon0%4==0)
#pragma unroll
        for (int dl = 0; dl < 4; ++dl) {      // in-register 8x4 transpose
            f16x8 vv;
#pragma unroll
            for (int j = 0; j < 8; ++j) vv[j] = (f16)L[j][dl];
            *(f16x8*)&xd[dl * 64 + (pbase ^ dl) * 8] = vv;
        }
        return;
    }
    if (bid < G0 + G1) {                      // wT[k][f][c] = W[f][c][k]
        const int e = (bid - G0) * 256 + tid;
        if (e < KS * 4096) {
            int c = e & 63, f = (e >> 6) & 63, k = e >> 12;
            wT[e] = (f16)weight[((size_t)(f * 64 + c)) * KS + k];
        }
        return;
    }
    {                                         // packed tap metadata, [k][lat][t]
        const int e = (bid - G0 - G1) * 256 + tid;
        if (e < NMETA) {
            int lat = (e / NPER) % NLAT;
            f16 pvh = (f16)psi_vals[e];
            u32 pb = (u32)__builtin_bit_cast(u16, pvh);
            int lonb = psi_lon_in[e] << 7;    // lon*128 B
            int4 m;
            m.x = (int)((pb << 16) | pb);
            m.y = (psi_lat_in[e] - lat + 1) * ROWB + lonb;  // combined byte base
            m.z = lonb;                                     // for wrap compare
            m.w = 0;
            meta[e] = m;
        }
    }
}

// ---------------- main (round-7, proven 108 us) -----------------------------
__global__ __launch_bounds__(768, 3) void disco_main(
    const f16* __restrict__ xT, const f16* __restrict__ wT,
    const int4* __restrict__ meta, const float* __restrict__ bias,
    float* __restrict__ out)
{
    extern __shared__ char xs[];              // [slot 3][lon 360][8 chunks x 8c]
    const int tid  = threadIdx.x;
    const int lane = tid & 63, wave = tid >> 6;   // 12 waves
    const int pn   = lane & 15, q = lane >> 4;
    const int half2 = blockIdx.x, lat = blockIdx.y, b = blockIdx.z;

    const int tile = half2 * 12 + wave;       // 0..11 | 12..23 (23 = dummy)
    const bool act = tile < 23;               // wave-uniform
    const int p  = tile * 16 + pn;            // <= 367; >=360 masked at store
    const int pl = p >= NLON ? p - NLON : p;
    const u32 plq  = (u32)((pl << 7) + (q << 4)); // p*128 + q*16
    const u32 plqm = plq - (u32)ROWB;             // wrapped variant
    const u32 thr  = (u32)((NLON - pl) << 7);     // wrap iff lon*128 >= thr

    const int rr0 = lat > 0 ? lat - 1 : 0;
    const int rr2 = lat < NLAT - 1 ? lat + 1 : NLAT - 1;

    // single stage: 3 rows x 64 channels (2880 f16x8 units per row)
    {
        const size_t bb = (size_t)b * NLAT;
        const f16* s0 = xT + (bb + rr0) * NLON * 64;
        const f16* s1 = xT + (bb + lat) * NLON * 64;
        const f16* s2 = xT + (bb + rr2) * NLON * 64;
        for (int i = tid; i < 2880; i += 768) {
            *(f16x8*)&xs[i * 16]             = *(const f16x8*)&s0[i * 8];
            *(f16x8*)&xs[ROWB + i * 16]      = *(const f16x8*)&s1[i * 8];
            *(f16x8*)&xs[2 * ROWB + i * 16]  = *(const f16x8*)&s2[i * 8];
        }
    }
    __syncthreads();                          // the ONLY barrier

    f32x4 D[4];
#pragma unroll
    for (int ft = 0; ft < 4; ++ft) D[ft] = (f32x4){0.f, 0.f, 0.f, 0.f};

    if (act) {
        for (int k = 0; k < KS; ++k) {
            f16x8 acc0 = (f16x8){0, 0, 0, 0, 0, 0, 0, 0};   // c = q*8+j
            f16x8 acc1 = (f16x8){0, 0, 0, 0, 0, 0, 0, 0};   // c = 32+q*8+j
            const int4* mp = meta + (k * NLAT + lat) * NPER;
#pragma unroll
            for (int tg = 0; tg < NPER; tg += 4) {
                int4 m[4];
#pragma unroll
                for (int j = 0; j < 4; ++j) m[j] = mp[tg + j];  // uniform -> s_load

                u32 a0[4], a1[4];
#pragma unroll
                for (int j = 0; j < 4; ++j) {
                    u32 ad = ((u32)m[j].z >= thr) ? plqm : plq; // cmp + cndmask
                    u32 t  = (u32)m[j].y + ad;
                    u32 a  = t ^ ((t >> 3) & 0x70u);            // chunk swizzle
                    a0[j] = a;
                    a1[j] = a ^ 64u;                            // upper c-half
                }
                f16x8 xv0[4], xv1[4];                           // 8 b128 in flight
#pragma unroll
                for (int j = 0; j < 4; ++j) xv0[j] = *(const f16x8*)(xs + a0[j]);
#pragma unroll
                for (int j = 0; j < 4; ++j) xv1[j] = *(const f16x8*)(xs + a1[j]);
#pragma unroll
                for (int j = 0; j < 4; ++j) {
                    u32 pk = (u32)m[j].x;
                    u32x4 pkv = {pk, pk, pk, pk};
                    f16x8 pf = __builtin_bit_cast(f16x8, pkv);
                    acc0 += xv0[j] * pf;                        // v_pk_fma_f16
                    acc1 += xv1[j] * pf;
                }
            }

            // A frags, both halves: wT[k][f][c], f = ft*16 + pn
            f16x8 Af0[4], Af1[4];
            const f16* wk = wT + (size_t)k * 4096 + q * 8;
#pragma unroll
            for (int ft = 0; ft < 4; ++ft) {
                Af0[ft] = *(const f16x8*)&wk[(ft * 16 + pn) * 64];        // c = q*8+j
                Af1[ft] = *(const f16x8*)&wk[32 + (ft * 16 + pn) * 64];   // +32
            }
#pragma unroll
            for (int ft = 0; ft < 4; ++ft) {
                D[ft] = __builtin_amdgcn_mfma_f32_16x16x32_f16(Af0[ft], acc0, D[ft], 0, 0, 0);
                D[ft] = __builtin_amdgcn_mfma_f32_16x16x32_f16(Af1[ft], acc1, D[ft], 0, 0, 0);
            }
        }
    }

    // epilogue: D[m=f][n=p], lane: col = pn, rows (lane>>4)*4 + r
    if (act && p < NLON) {
#pragma unroll
        for (int ft = 0; ft < 4; ++ft)
#pragma unroll
            for (int r = 0; r < 4; ++r) {
                const int f = ft * 16 + q * 4 + r;
                out[((size_t)(b * COUT + f) * NLAT + lat) * NLON + p] = D[ft][r] + bias[f];
            }
    }
}

extern "C" void kernel_launch(void* const* d_in, const int* in_sizes, int n_in,
                              void* d_out, int out_size, void* d_ws, size_t ws_size,
                              hipStream_t stream) {
    const float* x          = (const float*)d_in[0];
    const float* psi_vals   = (const float*)d_in[1];
    const float* weight     = (const float*)d_in[2];
    const float* bias       = (const float*)d_in[3];
    const int*   psi_lat_in = (const int*)d_in[6];
    const int*   psi_lon_in = (const int*)d_in[7];
    float* out = (float*)d_out;

    f16*  xT   = (f16*)d_ws;
    f16*  wT   = (f16*)((char*)d_ws + XT_BYTES);
    int4* meta = (int4*)((char*)d_ws + XT_BYTES + WT_BYTES);

    (void)hipFuncSetAttribute((const void*)disco_main,
                              hipFuncAttributeMaxDynamicSharedMemorySize, XS_BYTES);

    prep_kernel<<<dim3(G0 + G1 + G2), 256, 0, stream>>>(
        x, weight, psi_vals, psi_lat_in, psi_lon_in, xT, wT, meta);
    disco_main<<<dim3(2, NLAT, NB), 768, XS_BYTES, stream>>>(
        xT, wT, meta, bias, out);
}